// Round 22
// baseline (122.320 us; speedup 1.0000x reference)
//
#include <hip/hip_runtime.h>

#define NN 8192

typedef __bf16 bf16x8 __attribute__((ext_vector_type(8)));
typedef float f32x4 __attribute__((ext_vector_type(4)));
typedef unsigned short u16x8 __attribute__((ext_vector_type(8)));
typedef unsigned int u32x4 __attribute__((ext_vector_type(4)));
typedef unsigned long long u64x2 __attribute__((ext_vector_type(2)));
typedef int i32x4 __attribute__((ext_vector_type(4)));
typedef int i32x16 __attribute__((ext_vector_type(16)));

#define GLOBAL_AS __attribute__((address_space(1)))
#define LDS_AS __attribute__((address_space(3)))

__device__ __forceinline__ unsigned short f2bf(float f) {
  unsigned int u = __builtin_bit_cast(unsigned int, f);
  u += 0x7FFFu + ((u >> 16) & 1u);   // RNE
  return (unsigned short)(u >> 16);
}
__device__ __forceinline__ float bf2f(unsigned short b) {
  unsigned int u = ((unsigned int)b) << 16;
  return __builtin_bit_cast(float, u);
}

// 16 nibble-bytes (low 4 bits valid) -> 64 packed bits.
__device__ __forceinline__ unsigned long long merge16(uint4 B) {
  unsigned int t0 = (B.x | (B.x >> 4)) & 0x00FF00FFu; t0 = (t0 | (t0 >> 8)) & 0xFFFFu;
  unsigned int t1 = (B.y | (B.y >> 4)) & 0x00FF00FFu; t1 = (t1 | (t1 >> 8)) & 0xFFFFu;
  unsigned int t2 = (B.z | (B.z >> 4)) & 0x00FF00FFu; t2 = (t2 | (t2 >> 8)) & 0xFFFFu;
  unsigned int t3 = (B.w | (B.w >> 4)) & 0x00FF00FFu; t3 = (t3 | (t3 >> 8)) & 0xFFFFu;
  return (unsigned long long)(t0 | (t1 << 16))
       | ((unsigned long long)(t2 | (t3 << 16)) << 32);
}

// 16 adjacency bits (low 16 of h) -> 16 i8 {0,1} via bit-spread multiply.
__device__ __forceinline__ i32x4 expA(unsigned int h) {
  i32x4 a;
  a[0] = (int)((((h      ) & 0xFu) * 0x204081u) & 0x01010101u);
  a[1] = (int)((((h >> 4 ) & 0xFu) * 0x204081u) & 0x01010101u);
  a[2] = (int)((((h >> 8 ) & 0xFu) * 0x204081u) & 0x01010101u);
  a[3] = (int)((((h >> 12) & 0xFu) * 0x204081u) & 0x01010101u);
  return a;
}

// ---------------------------------------------------------------------------
// K0: packprep (fused, INTERLEAVED) -- R20 base + NONTEMPORAL everywhere:
// nt-loads on read-once streams (adj, x), nt-stores on bulk outputs
// (maskT, Yq, Sbf, degp).  R20 proved the read side of the L2-churn
// mechanism; this adds the write side.  (ext_vector types only -- the
// builtin rejects HIP struct vectors, R21's compile fail.)
// ---------------------------------------------------------------------------
__global__ __launch_bounds__(256) void packprep_kernel(
    const int* __restrict__ adj, unsigned long long* __restrict__ maskT,
    float* __restrict__ degp,
    const float* __restrict__ x, const float* __restrict__ Wself,
    const float* __restrict__ bself, const float* __restrict__ Wneigh,
    char* __restrict__ Yq, unsigned short* __restrict__ Sout) {
  __shared__ __align__(16) unsigned char xb[4][2048];     // pack: 8 KB (2 KB/wave)
  __shared__ __align__(16) unsigned short xa[64 * 64];    // prep: 8 KB
  __shared__ __align__(16) unsigned short bm[128 * 64];   // prep: 16 KB

  const unsigned int bid = blockIdx.x;
  if (bid >= 2048 || (bid & 1) == 0) {
    // ============================ pack v3 + nt ============================
    const int lane = threadIdx.x & 63;
    const int wv = threadIdx.x >> 6;
    const int pbk = (bid < 2048) ? (int)(bid >> 1) : (int)(bid - 1024); // 0..2047
    const int row0 = (pbk >> 3) << 5;            // 32-row group
    const int c0 = (pbk & 7) << 10;              // 1024-col octant
    const int Pb = (pbk & 7) << 3;               // 8 P entries of this octant
    const int* src = adj + (size_t)(row0 + (wv << 3)) * NN + c0;
#pragma unroll
    for (int r = 0; r < 8; ++r) {
#pragma unroll
      for (int c = 0; c < 4; ++c) {
        u32x4 v = __builtin_nontemporal_load(
            (const u32x4*)(src + (size_t)r * NN + c * 256 + lane * 4));
        unsigned int nib = (unsigned int)((int)v[0] > 0)
                         | ((unsigned int)((int)v[1] > 0) << 1)
                         | ((unsigned int)((int)v[2] > 0) << 2)
                         | ((unsigned int)((int)v[3] > 0) << 3);
        xb[wv][r * 256 + c * 64 + lane] = (unsigned char)nib;
      }
    }
    // wave-private tile: same-wave LDS ops ordered by lgkmcnt, no barrier.
    const int r = lane >> 3, k = lane & 7;       // lane -> (local row, P offset)
    uint4 B0 = *(const uint4*)&xb[wv][r * 256 + k * 32];
    uint4 B1 = *(const uint4*)&xb[wv][r * 256 + k * 32 + 16];
    unsigned long long w0 = merge16(B0);         // cols [P*128, +64)
    unsigned long long w1 = merge16(B1);         // cols [P*128+64, +64)
    const int grow = row0 + (wv << 3) + r;
    u64x2 e; e[0] = w0; e[1] = w1;
    __builtin_nontemporal_store(
        e, (u64x2*)&maskT[((size_t)(Pb + k) * NN + grow) * 2]);
    int dg = (int)__popcll(w0) + (int)__popcll(w1);
    dg += __shfl_xor(dg, 1);
    dg += __shfl_xor(dg, 2);
    dg += __shfl_xor(dg, 4);
    if (k == 0)
      __builtin_nontemporal_store((float)dg, &degp[(pbk & 7) * NN + grow]);
    return;
  }

  // ============================ prep ============================
  const int t = threadIdx.x;
  const int pb = (int)(bid >> 1);                // 0..1023
  const int b = pb >> 7;
  const int j0 = (pb & 127) << 6;

  {
    const float* Wsel = (t < 128) ? Wneigh : Wself;
    const int tt = t & 127;
    const int k = tt >> 1;
    const int c0 = (tt & 1) << 5;
    const int nbase = (t < 128) ? 0 : 64;
    const float4* src = (const float4*)(Wsel + k * 64 + c0);
#pragma unroll
    for (int q = 0; q < 8; ++q) {
      float4 v = src[q];
      int n0 = nbase + c0 + q * 4;
      int n;
      n = n0 + 0; bm[n * 64 + (k ^ ((n & 7) << 3))] = f2bf(v.x);
      n = n0 + 1; bm[n * 64 + (k ^ ((n & 7) << 3))] = f2bf(v.y);
      n = n0 + 2; bm[n * 64 + (k ^ ((n & 7) << 3))] = f2bf(v.z);
      n = n0 + 3; bm[n * 64 + (k ^ ((n & 7) << 3))] = f2bf(v.w);
    }
  }
  {
    const int j = t >> 2, q = t & 3;
    const float* xrow = x + ((size_t)b * NN + j0 + j) * 64 + q * 16;
    f32x4 v0 = __builtin_nontemporal_load((const f32x4*)(xrow + 0));
    f32x4 v1 = __builtin_nontemporal_load((const f32x4*)(xrow + 4));
    f32x4 v2 = __builtin_nontemporal_load((const f32x4*)(xrow + 8));
    f32x4 v3 = __builtin_nontemporal_load((const f32x4*)(xrow + 12));
    u16x8 p0, p1;
    p0[0] = f2bf(v0[0]); p0[1] = f2bf(v0[1]); p0[2] = f2bf(v0[2]); p0[3] = f2bf(v0[3]);
    p0[4] = f2bf(v1[0]); p0[5] = f2bf(v1[1]); p0[6] = f2bf(v1[2]); p0[7] = f2bf(v1[3]);
    p1[0] = f2bf(v2[0]); p1[1] = f2bf(v2[1]); p1[2] = f2bf(v2[2]); p1[3] = f2bf(v2[3]);
    p1[4] = f2bf(v3[0]); p1[5] = f2bf(v3[1]); p1[6] = f2bf(v3[2]); p1[7] = f2bf(v3[3]);
    const int base = q * 16;
    const int sw = (j & 7) << 3;
    *(u16x8*)&xa[j * 64 + (base ^ sw)] = p0;
    *(u16x8*)&xa[j * 64 + ((base + 8) ^ sw)] = p1;
  }
  __syncthreads();

  const int lane = t & 63, w = t >> 6;
  const int rl = lane & 15, hi = lane >> 4;
  f32x4 acc[8];
#pragma unroll
  for (int i = 0; i < 8; ++i) acc[i] = (f32x4){0.f, 0.f, 0.f, 0.f};

#pragma unroll
  for (int ks = 0; ks < 2; ++ks) {
    const int r = w * 16 + rl;
    const int kel = ks * 32 + hi * 8;
    bf16x8 af = __builtin_bit_cast(bf16x8, *(u16x8*)&xa[r * 64 + (kel ^ ((r & 7) << 3))]);
#pragma unroll
    for (int nf = 0; nf < 8; ++nf) {
      const int n = nf * 16 + rl;
      bf16x8 bv = __builtin_bit_cast(bf16x8, *(u16x8*)&bm[n * 64 + (kel ^ ((n & 7) << 3))]);
      acc[nf] = __builtin_amdgcn_mfma_f32_16x16x32_bf16(af, bv, acc[nf], 0, 0, 0);
    }
  }
#pragma unroll
  for (int nf = 0; nf < 8; ++nf) {
    if (nf < 4) {
      const int n = nf * 16 + rl;             // global col = b*64+n
      unsigned int pkt = 0;
#pragma unroll
      for (int r = 0; r < 4; ++r) {
        float v = fminf(fmaxf(acc[nf][r] * 16.0f, -127.0f), 127.0f);
        int iv = __float2int_rn(v);
        pkt |= ((unsigned int)(iv & 0xFF)) << (r * 8);
      }
      __builtin_nontemporal_store(
          pkt, (unsigned int*)(Yq + (size_t)(b * 64 + n) * NN + j0 + w * 16 + hi * 4));
    } else {
      const int fo = (nf - 4) * 16 + rl;
      const float bsv = bself[fo];
#pragma unroll
      for (int r = 0; r < 4; ++r) {
        const int jj = w * 16 + hi * 4 + r;
        __builtin_nontemporal_store(
            f2bf(acc[nf][r] + bsv),
            &Sout[((size_t)b * NN + j0 + jj) * 64 + fo]);
      }
    }
  }
}

// ---------------------------------------------------------------------------
// K2: big GEMM -- EXACT R11/R15/R18 config (measured 33.4 us) + nt C-write.
// BM=256 (4 waves x 64 rows), BN=64, ksp=2, grid 512 = 2 blocks/CU,
// 8-buffer 64 KB ring, staged 3 ahead, counted vmcnt(6), setprio.
// ---------------------------------------------------------------------------
__global__ __launch_bounds__(256, 2) void gemm_kernel(
    const i32x4* __restrict__ mask,     // maskT2: [64 P][8192 row] x 16B
    const char* __restrict__ Yq,        // [512][8192] i8
    unsigned short* __restrict__ Cp) {
  __shared__ __align__(16) char yL[8][8192];   // 64 KB ring
  const int tid = threadIdx.x;
  const int lane = tid & 63, w = tid >> 6;     // w = 0..3
  const int nid = ((blockIdx.x & 7) << 6) + (blockIdx.x >> 3);
  const int ksp = nid >> 8;
  const int nb = (nid >> 5) & 7;
  const int mb = nid & 31;
  const int i0 = mb << 8;            // 256 rows
  const int kbase = ksp << 12;       // k offset (elems)
  const int ncol0 = nb << 6;         // 64 cols
  const int l31 = lane & 31, l5 = lane >> 5;
  const int hs16 = l5 << 4;

  const int cst = (w << 4) + (lane >> 3);      // load0 col; load1 = +8
  const char* ysrc = Yq + (size_t)(ncol0 + cst) * NN + kbase
                     + (((lane & 7) ^ (cst & 7)) << 4);
  const i32x4* mqT = mask + ((size_t)(ksp << 5)) * NN + i0 + (w << 6) + l31;

  int boff[2][4];
#pragma unroll
  for (int nf = 0; nf < 2; ++nf)
#pragma unroll
    for (int s = 0; s < 4; ++s) {
      const int col = (nf << 5) + l31;
      const int g = (s << 1) + l5;
      boff[nf][s] = (col << 7) + ((g ^ (col & 7)) << 4);
    }

  i32x16 acc[2][2];
#pragma unroll
  for (int mf = 0; mf < 2; ++mf)
#pragma unroll
    for (int nf = 0; nf < 2; ++nf)
#pragma unroll
      for (int e = 0; e < 16; ++e) acc[mf][nf][e] = 0;

#define BARRIER  __builtin_amdgcn_s_barrier()
#define MEMBAR   asm volatile("" ::: "memory")
#define WAIT_VM6 asm volatile("s_waitcnt vmcnt(6)" ::: "memory")

#define STAGE(t)                                                              \
  {                                                                           \
    __builtin_amdgcn_global_load_lds(                                         \
        (GLOBAL_AS void*)const_cast<char*>(ysrc + (size_t)((t) & 31) * 128),  \
        (LDS_AS void*)&yL[(t) & 7][w << 11], 16, 0, 0);                       \
    __builtin_amdgcn_global_load_lds(                                         \
        (GLOBAL_AS void*)const_cast<char*>(ysrc + (size_t)8 * NN              \
                                           + (size_t)((t) & 31) * 128),       \
        (LDS_AS void*)&yL[(t) & 7][(w << 11) + 1024], 16, 0, 0);              \
  }

#define LOADM(M0, M1, t)                                                      \
  { M0 = mqT[(size_t)((t) & 31) * NN]; M1 = mqT[(size_t)((t) & 31) * NN + 32]; }

#define COMPUTE(t, M0, M1)                                                    \
  {                                                                           \
    const char* yb_ = &yL[(t) & 7][0];                                        \
    __builtin_amdgcn_s_setprio(1);                                            \
    _Pragma("unroll")                                                         \
    for (int s_ = 0; s_ < 4; ++s_) {                                          \
      i32x4 b0_ = *(const i32x4*)(yb_ + boff[0][s_]);                         \
      i32x4 b1_ = *(const i32x4*)(yb_ + boff[1][s_]);                         \
      unsigned int h0_ = (unsigned int)(M0)[s_] >> hs16;                      \
      unsigned int h1_ = (unsigned int)(M1)[s_] >> hs16;                      \
      i32x4 a0_ = expA(h0_);                                                  \
      i32x4 a1_ = expA(h1_);                                                  \
      acc[0][0] = __builtin_amdgcn_mfma_i32_32x32x32_i8(a0_, b0_, acc[0][0], 0, 0, 0); \
      acc[0][1] = __builtin_amdgcn_mfma_i32_32x32x32_i8(a0_, b1_, acc[0][1], 0, 0, 0); \
      acc[1][0] = __builtin_amdgcn_mfma_i32_32x32x32_i8(a1_, b0_, acc[1][0], 0, 0, 0); \
      acc[1][1] = __builtin_amdgcn_mfma_i32_32x32x32_i8(a1_, b1_, acc[1][1], 0, 0, 0); \
    }                                                                         \
    __builtin_amdgcn_s_setprio(0);                                            \
  }

  i32x4 Ma0, Ma1, Mb0, Mb1;
  STAGE(0);
  STAGE(1);
  STAGE(2);
  LOADM(Ma0, Ma1, 0);

  for (int t2 = 0; t2 < 32; t2 += 2) {
    LOADM(Mb0, Mb1, t2 + 1);
    STAGE(t2 + 3);
    WAIT_VM6;
    BARRIER; MEMBAR;
    COMPUTE(t2, Ma0, Ma1);
    LOADM(Ma0, Ma1, t2 + 2);
    STAGE(t2 + 4);
    WAIT_VM6;
    BARRIER; MEMBAR;
    COMPUTE(t2 + 1, Mb0, Mb1);
  }
  asm volatile("s_waitcnt vmcnt(0)" ::: "memory");

#pragma unroll
  for (int mf = 0; mf < 2; ++mf)
#pragma unroll
    for (int nf = 0; nf < 2; ++nf) {
      const int col = ncol0 + (nf << 5) + l31;
#pragma unroll
      for (int r = 0; r < 16; ++r) {
        const int row = i0 + (w << 6) + (mf << 5) + (r & 3) + ((r >> 2) << 3) + (l5 << 2);
        __builtin_nontemporal_store(
            f2bf((float)acc[mf][nf][r] * 0.0625f),
            &Cp[((size_t)ksp * NN + row) * 512 + col]);
      }
    }
#undef BARRIER
#undef MEMBAR
#undef WAIT_VM6
#undef STAGE
#undef LOADM
#undef COMPUTE
}

// ---------------------------------------------------------------------------
// K3: epi (fused).  One 64-lane wave per (b,i); lane = fo.
// deg = sum of 8 column-octant partials.  nt on read-once streams + out.
// v = relu(S + [deg>0]*((Cp0+Cp1)/max(deg,1) + b_neigh)); LayerNorm; f32 out.
// ---------------------------------------------------------------------------
__global__ __launch_bounds__(256) void epi_kernel(
    const unsigned short* __restrict__ Cp, const float* __restrict__ degp,
    const unsigned short* __restrict__ Sbf, const float* __restrict__ bneigh,
    const float* __restrict__ gamma, const float* __restrict__ beta,
    float* __restrict__ out) {
  const int lane = threadIdx.x & 63;
  const int wid = (blockIdx.x << 2) + (threadIdx.x >> 6);
  const int b = wid >> 13;
  const int i = wid & (NN - 1);
  float deg = 0.0f;
#pragma unroll
  for (int cb = 0; cb < 8; ++cb) deg += degp[cb * NN + i];
  const float rdeg = 1.0f / fmaxf(deg, 1.0f);
  const size_t cidx = (size_t)i * 512 + b * 64 + lane;
  const float c = bf2f(__builtin_nontemporal_load(&Cp[cidx]))
                + bf2f(__builtin_nontemporal_load(&Cp[(size_t)NN * 512 + cidx]));
  const float sv = bf2f(__builtin_nontemporal_load(&Sbf[((size_t)b * NN + i) * 64 + lane]));
  float v = sv + ((deg > 0.5f) ? (c * rdeg + bneigh[lane]) : 0.0f);
  v = fmaxf(v, 0.0f);
  float s1 = v, s2 = v * v;
#pragma unroll
  for (int m = 1; m < 64; m <<= 1) {
    s1 += __shfl_xor(s1, m);
    s2 += __shfl_xor(s2, m);
  }
  const float mu = s1 * 0.015625f;
  const float var = s2 * 0.015625f - mu * mu;
  const float o = (v - mu) * rsqrtf(var + 1e-5f) * gamma[lane] + beta[lane];
  __builtin_nontemporal_store(o, &out[((size_t)b * NN + i) * 64 + lane]);
}

extern "C" void kernel_launch(void* const* d_in, const int* in_sizes, int n_in,
                              void* d_out, int out_size, void* d_ws, size_t ws_size,
                              hipStream_t stream) {
  (void)in_sizes; (void)n_in; (void)out_size; (void)ws_size;
  const float* x      = (const float*)d_in[0];
  const int*   adj    = (const int*)d_in[1];
  const float* Wself  = (const float*)d_in[2];
  const float* bself  = (const float*)d_in[3];
  const float* Wneigh = (const float*)d_in[4];
  const float* bneigh = (const float*)d_in[5];
  const float* gamma  = (const float*)d_in[6];
  const float* beta   = (const float*)d_in[7];
  char* ws = (char*)d_ws;
  char*               Yq    = ws;                                    //  4 MB
  unsigned long long* maskT = (unsigned long long*)(ws + 4194304);   //  8 MB (transposed)
  unsigned short*     Sbf   = (unsigned short*)(ws + 12582912);      //  8 MB
  unsigned short*     Cp    = (unsigned short*)(ws + 20971520);      // 16.7 MB (2 planes)
  float*              degp  = (float*)(ws + 37748736);               // 256 KB (8 partials)
  float*              out   = (float*)d_out;

  packprep_kernel<<<dim3(3072), dim3(256), 0, stream>>>(
      adj, maskT, degp, x, Wself, bself, Wneigh, Yq, Sbf);
  gemm_kernel<<<dim3(512), dim3(256), 0, stream>>>((const i32x4*)maskT, Yq, Cp);
  epi_kernel<<<dim3(16384), dim3(256), 0, stream>>>(Cp, degp, Sbf, bneigh, gamma, beta, out);
}

// Round 23
// 108.031 us; speedup vs baseline: 1.1323x; 1.1323x over previous
//
#include <hip/hip_runtime.h>

#define NN 8192

typedef __bf16 bf16x8 __attribute__((ext_vector_type(8)));
typedef float f32x4 __attribute__((ext_vector_type(4)));
typedef unsigned short u16x8 __attribute__((ext_vector_type(8)));
typedef unsigned int u32x4 __attribute__((ext_vector_type(4)));
typedef int i32x4 __attribute__((ext_vector_type(4)));
typedef int i32x16 __attribute__((ext_vector_type(16)));

#define GLOBAL_AS __attribute__((address_space(1)))
#define LDS_AS __attribute__((address_space(3)))

__device__ __forceinline__ unsigned short f2bf(float f) {
  unsigned int u = __builtin_bit_cast(unsigned int, f);
  u += 0x7FFFu + ((u >> 16) & 1u);   // RNE
  return (unsigned short)(u >> 16);
}
__device__ __forceinline__ float bf2f(unsigned short b) {
  unsigned int u = ((unsigned int)b) << 16;
  return __builtin_bit_cast(float, u);
}

// 16 nibble-bytes (low 4 bits valid) -> 64 packed bits.
__device__ __forceinline__ unsigned long long merge16(uint4 B) {
  unsigned int t0 = (B.x | (B.x >> 4)) & 0x00FF00FFu; t0 = (t0 | (t0 >> 8)) & 0xFFFFu;
  unsigned int t1 = (B.y | (B.y >> 4)) & 0x00FF00FFu; t1 = (t1 | (t1 >> 8)) & 0xFFFFu;
  unsigned int t2 = (B.z | (B.z >> 4)) & 0x00FF00FFu; t2 = (t2 | (t2 >> 8)) & 0xFFFFu;
  unsigned int t3 = (B.w | (B.w >> 4)) & 0x00FF00FFu; t3 = (t3 | (t3 >> 8)) & 0xFFFFu;
  return (unsigned long long)(t0 | (t1 << 16))
       | ((unsigned long long)(t2 | (t3 << 16)) << 32);
}

// 16 adjacency bits (low 16 of h) -> 16 i8 {0,1} via bit-spread multiply.
__device__ __forceinline__ i32x4 expA(unsigned int h) {
  i32x4 a;
  a[0] = (int)((((h      ) & 0xFu) * 0x204081u) & 0x01010101u);
  a[1] = (int)((((h >> 4 ) & 0xFu) * 0x204081u) & 0x01010101u);
  a[2] = (int)((((h >> 8 ) & 0xFu) * 0x204081u) & 0x01010101u);
  a[3] = (int)((((h >> 12) & 0xFu) * 0x204081u) & 0x01010101u);
  return a;
}

// ---------------------------------------------------------------------------
// K0: packprep (fused, INTERLEAVED) -- R20 config (best: 108.6 us).
// nt-LOADS on adj only (read-once stream -> no L2 allocation churn; R20
// win).  Regular stores on ALL intermediates (maskT/Yq/Sbf are consumed by
// the next kernels -> keep them cache-resident; R22 proved nt-stores here
// cost +13.7 us).
// bids [0,2048): even -> pack, odd -> prep; [2048,3072): pack.
// ---------------------------------------------------------------------------
__global__ __launch_bounds__(256) void packprep_kernel(
    const int* __restrict__ adj, unsigned long long* __restrict__ maskT,
    float* __restrict__ degp,
    const float* __restrict__ x, const float* __restrict__ Wself,
    const float* __restrict__ bself, const float* __restrict__ Wneigh,
    char* __restrict__ Yq, unsigned short* __restrict__ Sout) {
  __shared__ __align__(16) unsigned char xb[4][2048];     // pack: 8 KB (2 KB/wave)
  __shared__ __align__(16) unsigned short xa[64 * 64];    // prep: 8 KB
  __shared__ __align__(16) unsigned short bm[128 * 64];   // prep: 16 KB

  const unsigned int bid = blockIdx.x;
  if (bid >= 2048 || (bid & 1) == 0) {
    // ============================ pack v3 + nt-load ============================
    const int lane = threadIdx.x & 63;
    const int wv = threadIdx.x >> 6;
    const int pbk = (bid < 2048) ? (int)(bid >> 1) : (int)(bid - 1024); // 0..2047
    const int row0 = (pbk >> 3) << 5;            // 32-row group
    const int c0 = (pbk & 7) << 10;              // 1024-col octant
    const int Pb = (pbk & 7) << 3;               // 8 P entries of this octant
    const int* src = adj + (size_t)(row0 + (wv << 3)) * NN + c0;
#pragma unroll
    for (int r = 0; r < 8; ++r) {
#pragma unroll
      for (int c = 0; c < 4; ++c) {
        u32x4 v = __builtin_nontemporal_load(
            (const u32x4*)(src + (size_t)r * NN + c * 256 + lane * 4));
        unsigned int nib = (unsigned int)((int)v[0] > 0)
                         | ((unsigned int)((int)v[1] > 0) << 1)
                         | ((unsigned int)((int)v[2] > 0) << 2)
                         | ((unsigned int)((int)v[3] > 0) << 3);
        xb[wv][r * 256 + c * 64 + lane] = (unsigned char)nib;
      }
    }
    // wave-private tile: same-wave LDS ops ordered by lgkmcnt, no barrier.
    const int r = lane >> 3, k = lane & 7;       // lane -> (local row, P offset)
    uint4 B0 = *(const uint4*)&xb[wv][r * 256 + k * 32];
    uint4 B1 = *(const uint4*)&xb[wv][r * 256 + k * 32 + 16];
    unsigned long long w0 = merge16(B0);         // cols [P*128, +64)
    unsigned long long w1 = merge16(B1);         // cols [P*128+64, +64)
    const int grow = row0 + (wv << 3) + r;
    ulonglong2 e; e.x = w0; e.y = w1;
    *(ulonglong2*)&maskT[((size_t)(Pb + k) * NN + grow) * 2] = e;
    int dg = (int)__popcll(w0) + (int)__popcll(w1);
    dg += __shfl_xor(dg, 1);
    dg += __shfl_xor(dg, 2);
    dg += __shfl_xor(dg, 4);
    if (k == 0) degp[(pbk & 7) * NN + grow] = (float)dg;
    return;
  }

  // ============================ prep ============================
  const int t = threadIdx.x;
  const int pb = (int)(bid >> 1);                // 0..1023
  const int b = pb >> 7;
  const int j0 = (pb & 127) << 6;

  {
    const float* Wsel = (t < 128) ? Wneigh : Wself;
    const int tt = t & 127;
    const int k = tt >> 1;
    const int c0 = (tt & 1) << 5;
    const int nbase = (t < 128) ? 0 : 64;
    const float4* src = (const float4*)(Wsel + k * 64 + c0);
#pragma unroll
    for (int q = 0; q < 8; ++q) {
      float4 v = src[q];
      int n0 = nbase + c0 + q * 4;
      int n;
      n = n0 + 0; bm[n * 64 + (k ^ ((n & 7) << 3))] = f2bf(v.x);
      n = n0 + 1; bm[n * 64 + (k ^ ((n & 7) << 3))] = f2bf(v.y);
      n = n0 + 2; bm[n * 64 + (k ^ ((n & 7) << 3))] = f2bf(v.z);
      n = n0 + 3; bm[n * 64 + (k ^ ((n & 7) << 3))] = f2bf(v.w);
    }
  }
  {
    const int j = t >> 2, q = t & 3;
    const float* xrow = x + ((size_t)b * NN + j0 + j) * 64 + q * 16;
    float4 v0 = *(const float4*)(xrow + 0);
    float4 v1 = *(const float4*)(xrow + 4);
    float4 v2 = *(const float4*)(xrow + 8);
    float4 v3 = *(const float4*)(xrow + 12);
    u16x8 p0, p1;
    p0[0] = f2bf(v0.x); p0[1] = f2bf(v0.y); p0[2] = f2bf(v0.z); p0[3] = f2bf(v0.w);
    p0[4] = f2bf(v1.x); p0[5] = f2bf(v1.y); p0[6] = f2bf(v1.z); p0[7] = f2bf(v1.w);
    p1[0] = f2bf(v2.x); p1[1] = f2bf(v2.y); p1[2] = f2bf(v2.z); p1[3] = f2bf(v2.w);
    p1[4] = f2bf(v3.x); p1[5] = f2bf(v3.y); p1[6] = f2bf(v3.z); p1[7] = f2bf(v3.w);
    const int base = q * 16;
    const int sw = (j & 7) << 3;
    *(u16x8*)&xa[j * 64 + (base ^ sw)] = p0;
    *(u16x8*)&xa[j * 64 + ((base + 8) ^ sw)] = p1;
  }
  __syncthreads();

  const int lane = t & 63, w = t >> 6;
  const int rl = lane & 15, hi = lane >> 4;
  f32x4 acc[8];
#pragma unroll
  for (int i = 0; i < 8; ++i) acc[i] = (f32x4){0.f, 0.f, 0.f, 0.f};

#pragma unroll
  for (int ks = 0; ks < 2; ++ks) {
    const int r = w * 16 + rl;
    const int kel = ks * 32 + hi * 8;
    bf16x8 af = __builtin_bit_cast(bf16x8, *(u16x8*)&xa[r * 64 + (kel ^ ((r & 7) << 3))]);
#pragma unroll
    for (int nf = 0; nf < 8; ++nf) {
      const int n = nf * 16 + rl;
      bf16x8 bv = __builtin_bit_cast(bf16x8, *(u16x8*)&bm[n * 64 + (kel ^ ((n & 7) << 3))]);
      acc[nf] = __builtin_amdgcn_mfma_f32_16x16x32_bf16(af, bv, acc[nf], 0, 0, 0);
    }
  }
#pragma unroll
  for (int nf = 0; nf < 8; ++nf) {
    if (nf < 4) {
      const int n = nf * 16 + rl;             // global col = b*64+n
      unsigned int pkt = 0;
#pragma unroll
      for (int r = 0; r < 4; ++r) {
        float v = fminf(fmaxf(acc[nf][r] * 16.0f, -127.0f), 127.0f);
        int iv = __float2int_rn(v);
        pkt |= ((unsigned int)(iv & 0xFF)) << (r * 8);
      }
      *(unsigned int*)(Yq + (size_t)(b * 64 + n) * NN + j0 + w * 16 + hi * 4) = pkt;
    } else {
      const int fo = (nf - 4) * 16 + rl;
      const float bsv = bself[fo];
#pragma unroll
      for (int r = 0; r < 4; ++r) {
        const int jj = w * 16 + hi * 4 + r;
        Sout[((size_t)b * NN + j0 + jj) * 64 + fo] = f2bf(acc[nf][r] + bsv);
      }
    }
  }
}

// ---------------------------------------------------------------------------
// K2: big GEMM -- EXACT R11/R15/R18/R20 config (measured 33.4 us):
// BM=256 (4 waves x 64 rows), BN=64, ksp=2, grid 512 = 2 blocks/CU,
// 8-buffer 64 KB ring, staged 3 ahead, counted vmcnt(6), setprio.
// ---------------------------------------------------------------------------
__global__ __launch_bounds__(256, 2) void gemm_kernel(
    const i32x4* __restrict__ mask,     // maskT2: [64 P][8192 row] x 16B
    const char* __restrict__ Yq,        // [512][8192] i8
    unsigned short* __restrict__ Cp) {
  __shared__ __align__(16) char yL[8][8192];   // 64 KB ring
  const int tid = threadIdx.x;
  const int lane = tid & 63, w = tid >> 6;     // w = 0..3
  const int nid = ((blockIdx.x & 7) << 6) + (blockIdx.x >> 3);
  const int ksp = nid >> 8;
  const int nb = (nid >> 5) & 7;
  const int mb = nid & 31;
  const int i0 = mb << 8;            // 256 rows
  const int kbase = ksp << 12;       // k offset (elems)
  const int ncol0 = nb << 6;         // 64 cols
  const int l31 = lane & 31, l5 = lane >> 5;
  const int hs16 = l5 << 4;

  const int cst = (w << 4) + (lane >> 3);      // load0 col; load1 = +8
  const char* ysrc = Yq + (size_t)(ncol0 + cst) * NN + kbase
                     + (((lane & 7) ^ (cst & 7)) << 4);
  const i32x4* mqT = mask + ((size_t)(ksp << 5)) * NN + i0 + (w << 6) + l31;

  int boff[2][4];
#pragma unroll
  for (int nf = 0; nf < 2; ++nf)
#pragma unroll
    for (int s = 0; s < 4; ++s) {
      const int col = (nf << 5) + l31;
      const int g = (s << 1) + l5;
      boff[nf][s] = (col << 7) + ((g ^ (col & 7)) << 4);
    }

  i32x16 acc[2][2];
#pragma unroll
  for (int mf = 0; mf < 2; ++mf)
#pragma unroll
    for (int nf = 0; nf < 2; ++nf)
#pragma unroll
      for (int e = 0; e < 16; ++e) acc[mf][nf][e] = 0;

#define BARRIER  __builtin_amdgcn_s_barrier()
#define MEMBAR   asm volatile("" ::: "memory")
#define WAIT_VM6 asm volatile("s_waitcnt vmcnt(6)" ::: "memory")

#define STAGE(t)                                                              \
  {                                                                           \
    __builtin_amdgcn_global_load_lds(                                         \
        (GLOBAL_AS void*)const_cast<char*>(ysrc + (size_t)((t) & 31) * 128),  \
        (LDS_AS void*)&yL[(t) & 7][w << 11], 16, 0, 0);                       \
    __builtin_amdgcn_global_load_lds(                                         \
        (GLOBAL_AS void*)const_cast<char*>(ysrc + (size_t)8 * NN              \
                                           + (size_t)((t) & 31) * 128),       \
        (LDS_AS void*)&yL[(t) & 7][(w << 11) + 1024], 16, 0, 0);              \
  }

#define LOADM(M0, M1, t)                                                      \
  { M0 = mqT[(size_t)((t) & 31) * NN]; M1 = mqT[(size_t)((t) & 31) * NN + 32]; }

#define COMPUTE(t, M0, M1)                                                    \
  {                                                                           \
    const char* yb_ = &yL[(t) & 7][0];                                        \
    __builtin_amdgcn_s_setprio(1);                                            \
    _Pragma("unroll")                                                         \
    for (int s_ = 0; s_ < 4; ++s_) {                                          \
      i32x4 b0_ = *(const i32x4*)(yb_ + boff[0][s_]);                         \
      i32x4 b1_ = *(const i32x4*)(yb_ + boff[1][s_]);                         \
      unsigned int h0_ = (unsigned int)(M0)[s_] >> hs16;                      \
      unsigned int h1_ = (unsigned int)(M1)[s_] >> hs16;                      \
      i32x4 a0_ = expA(h0_);                                                  \
      i32x4 a1_ = expA(h1_);                                                  \
      acc[0][0] = __builtin_amdgcn_mfma_i32_32x32x32_i8(a0_, b0_, acc[0][0], 0, 0, 0); \
      acc[0][1] = __builtin_amdgcn_mfma_i32_32x32x32_i8(a0_, b1_, acc[0][1], 0, 0, 0); \
      acc[1][0] = __builtin_amdgcn_mfma_i32_32x32x32_i8(a1_, b0_, acc[1][0], 0, 0, 0); \
      acc[1][1] = __builtin_amdgcn_mfma_i32_32x32x32_i8(a1_, b1_, acc[1][1], 0, 0, 0); \
    }                                                                         \
    __builtin_amdgcn_s_setprio(0);                                            \
  }

  i32x4 Ma0, Ma1, Mb0, Mb1;
  STAGE(0);
  STAGE(1);
  STAGE(2);
  LOADM(Ma0, Ma1, 0);

  for (int t2 = 0; t2 < 32; t2 += 2) {
    LOADM(Mb0, Mb1, t2 + 1);
    STAGE(t2 + 3);
    WAIT_VM6;
    BARRIER; MEMBAR;
    COMPUTE(t2, Ma0, Ma1);
    LOADM(Ma0, Ma1, t2 + 2);
    STAGE(t2 + 4);
    WAIT_VM6;
    BARRIER; MEMBAR;
    COMPUTE(t2 + 1, Mb0, Mb1);
  }
  asm volatile("s_waitcnt vmcnt(0)" ::: "memory");

#pragma unroll
  for (int mf = 0; mf < 2; ++mf)
#pragma unroll
    for (int nf = 0; nf < 2; ++nf) {
      const int col = ncol0 + (nf << 5) + l31;
#pragma unroll
      for (int r = 0; r < 16; ++r) {
        const int row = i0 + (w << 6) + (mf << 5) + (r & 3) + ((r >> 2) << 3) + (l5 << 2);
        Cp[((size_t)ksp * NN + row) * 512 + col] = f2bf((float)acc[mf][nf][r] * 0.0625f);
      }
    }
#undef BARRIER
#undef MEMBAR
#undef WAIT_VM6
#undef STAGE
#undef LOADM
#undef COMPUTE
}

// ---------------------------------------------------------------------------
// K3: epi (fused).  One 64-lane wave per (b,i); lane = fo.
// deg = sum of 8 column-octant partials.  nt-store ONLY on the final out
// (never re-read on device; safe residue of R22).
// v = relu(S + [deg>0]*((Cp0+Cp1)/max(deg,1) + b_neigh)); LayerNorm; f32 out.
// ---------------------------------------------------------------------------
__global__ __launch_bounds__(256) void epi_kernel(
    const unsigned short* __restrict__ Cp, const float* __restrict__ degp,
    const unsigned short* __restrict__ Sbf, const float* __restrict__ bneigh,
    const float* __restrict__ gamma, const float* __restrict__ beta,
    float* __restrict__ out) {
  const int lane = threadIdx.x & 63;
  const int wid = (blockIdx.x << 2) + (threadIdx.x >> 6);
  const int b = wid >> 13;
  const int i = wid & (NN - 1);
  float deg = 0.0f;
#pragma unroll
  for (int cb = 0; cb < 8; ++cb) deg += degp[cb * NN + i];
  const float rdeg = 1.0f / fmaxf(deg, 1.0f);
  const size_t cidx = (size_t)i * 512 + b * 64 + lane;
  const float c = bf2f(Cp[cidx]) + bf2f(Cp[(size_t)NN * 512 + cidx]);
  const float sv = bf2f(Sbf[((size_t)b * NN + i) * 64 + lane]);
  float v = sv + ((deg > 0.5f) ? (c * rdeg + bneigh[lane]) : 0.0f);
  v = fmaxf(v, 0.0f);
  float s1 = v, s2 = v * v;
#pragma unroll
  for (int m = 1; m < 64; m <<= 1) {
    s1 += __shfl_xor(s1, m);
    s2 += __shfl_xor(s2, m);
  }
  const float mu = s1 * 0.015625f;
  const float var = s2 * 0.015625f - mu * mu;
  const float o = (v - mu) * rsqrtf(var + 1e-5f) * gamma[lane] + beta[lane];
  __builtin_nontemporal_store(o, &out[((size_t)b * NN + i) * 64 + lane]);
}

extern "C" void kernel_launch(void* const* d_in, const int* in_sizes, int n_in,
                              void* d_out, int out_size, void* d_ws, size_t ws_size,
                              hipStream_t stream) {
  (void)in_sizes; (void)n_in; (void)out_size; (void)ws_size;
  const float* x      = (const float*)d_in[0];
  const int*   adj    = (const int*)d_in[1];
  const float* Wself  = (const float*)d_in[2];
  const float* bself  = (const float*)d_in[3];
  const float* Wneigh = (const float*)d_in[4];
  const float* bneigh = (const float*)d_in[5];
  const float* gamma  = (const float*)d_in[6];
  const float* beta   = (const float*)d_in[7];
  char* ws = (char*)d_ws;
  char*               Yq    = ws;                                    //  4 MB
  unsigned long long* maskT = (unsigned long long*)(ws + 4194304);   //  8 MB (transposed)
  unsigned short*     Sbf   = (unsigned short*)(ws + 12582912);      //  8 MB
  unsigned short*     Cp    = (unsigned short*)(ws + 20971520);      // 16.7 MB (2 planes)
  float*              degp  = (float*)(ws + 37748736);               // 256 KB (8 partials)
  float*              out   = (float*)d_out;

  packprep_kernel<<<dim3(3072), dim3(256), 0, stream>>>(
      adj, maskT, degp, x, Wself, bself, Wneigh, Yq, Sbf);
  gemm_kernel<<<dim3(512), dim3(256), 0, stream>>>((const i32x4*)maskT, Yq, Cp);
  epi_kernel<<<dim3(16384), dim3(256), 0, stream>>>(Cp, degp, Sbf, bneigh, gamma, beta, out);
}